// Round 1
// baseline (243.257 us; speedup 1.0000x reference)
//
#include <hip/hip_runtime.h>
#include <hip/hip_bf16.h>
#include <stdint.h>

#define DIM 512

typedef __bf16 bf16x8 __attribute__((ext_vector_type(8)));
typedef float f32x4 __attribute__((ext_vector_type(4)));

// ---- monotonic float<->uint encoding for atomicMax on signed floats ----
__device__ __forceinline__ unsigned fenc(float f) {
  unsigned u = __float_as_uint(f);
  return (u & 0x80000000u) ? ~u : (u | 0x80000000u);
}
__device__ __forceinline__ float fdec(unsigned e) {
  unsigned u = (e & 0x80000000u) ? (e & 0x7FFFFFFFu) : ~e;
  return __uint_as_float(u);
}

// ---- transpose last-2-dims + f32->bf16 convert: out[z][i][j] = in[z][j][i] ----
__global__ __launch_bounds__(256) void k_transpose_bf16(const float* __restrict__ in,
                                                        __hip_bfloat16* __restrict__ out) {
  __shared__ float tile[32][33];
  int x0 = blockIdx.x * 32, y0 = blockIdx.y * 32, z = blockIdx.z;
  const float* src = in + (size_t)z * DIM * DIM;
  __hip_bfloat16* dst = out + (size_t)z * DIM * DIM;
  int tx = threadIdx.x, ty = threadIdx.y;
#pragma unroll
  for (int k = 0; k < 4; ++k)
    tile[ty + 8 * k][tx] = src[(size_t)(y0 + ty + 8 * k) * DIM + x0 + tx];
  __syncthreads();
#pragma unroll
  for (int k = 0; k < 4; ++k)
    dst[(size_t)(x0 + ty + 8 * k) * DIM + y0 + tx] = __float2bfloat16(tile[tx][ty + 8 * k]);
}

// ---- init max buffers to enc(-inf) ----
__global__ void k_init_max(unsigned* p) { p[blockIdx.x * 256 + threadIdx.x] = 0x007FFFFFu; }

// ---- async global->LDS, 16B per lane ----
__device__ __forceinline__ void gload_lds16(const __hip_bfloat16* g, __hip_bfloat16* l) {
  __builtin_amdgcn_global_load_lds(
      (const __attribute__((address_space(1))) uint32_t*)g,
      (__attribute__((address_space(3))) uint32_t*)l, 16, 0, 0);
}

// ---- MFMA GEMM: C(128x128 tile) = X(M,K=512 row-major) @ Yt(N,K=512 row-major)^T
// EPI=0: store bf16 proj.  EPI=1: tanh + mask + row/col max -> atomicMax.
template <int EPI>
__global__ __launch_bounds__(256, 2) void k_gemm_bt(
    const __hip_bfloat16* __restrict__ Xbase, const __hip_bfloat16* __restrict__ Ytbase,
    const float* __restrict__ msk, __hip_bfloat16* __restrict__ projOut,
    unsigned* __restrict__ maxS, unsigned* __restrict__ maxT) {
  __shared__ __align__(16) __hip_bfloat16 lA[128 * 64];
  __shared__ __align__(16) __hip_bfloat16 lB[128 * 64];
  const int tid = threadIdx.x;
  const int lane = tid & 63;
  const int wid = tid >> 6;
  const int wm = wid >> 1, wn = wid & 1;
  const int tileid = blockIdx.x;
  const int bm = tileid & 3, bn = tileid >> 2;
  const int z = blockIdx.y;

  const __hip_bfloat16* X;
  const __hip_bfloat16* Yt;
  if (EPI == 0) {
    X = Xbase + (size_t)z * DIM * DIM;
    Yt = Ytbase;
  } else {
    int a = z >> 4, b = z & 15;
    X = Xbase + (size_t)a * DIM * DIM;
    Yt = Ytbase + (size_t)b * DIM * DIM;
  }

  // staging: thread t covers 16B slot (i*256+t); LDS dest is linear (HW requirement),
  // global source column is pre-XOR-swizzled so reads can use the same involution.
  int sl16[4], srow[4], scol[4];
#pragma unroll
  for (int i = 0; i < 4; ++i) {
    int d16 = i * 256 + tid;       // 16B-slot index within 128x64 bf16 tile
    int r = d16 >> 3, p = d16 & 7; // row, physical 16B slot in row
    sl16[i] = d16;
    srow[i] = r;
    scol[i] = (p ^ (r & 7)) * 8;   // logical bf16 column
  }

  f32x4 acc[4][4];
#pragma unroll
  for (int mi = 0; mi < 4; ++mi)
#pragma unroll
    for (int ni = 0; ni < 4; ++ni) acc[mi][ni] = (f32x4){0.f, 0.f, 0.f, 0.f};

  const int rowA = bm * 128, rowB = bn * 128;
  for (int k0 = 0; k0 < DIM; k0 += 64) {
#pragma unroll
    for (int i = 0; i < 4; ++i) {
      gload_lds16(X + (size_t)(rowA + srow[i]) * DIM + k0 + scol[i], &lA[sl16[i] * 8]);
      gload_lds16(Yt + (size_t)(rowB + srow[i]) * DIM + k0 + scol[i], &lB[sl16[i] * 8]);
    }
    __syncthreads();
#pragma unroll
    for (int ks = 0; ks < 2; ++ks) {
      bf16x8 af[4], bfr[4];
#pragma unroll
      for (int mi = 0; mi < 4; ++mi) {
        int r = wm * 64 + mi * 16 + (lane & 15);
        int sl = ks * 4 + (lane >> 4);
        int p = sl ^ (r & 7);
        af[mi] = *(const bf16x8*)&lA[r * 64 + p * 8];
      }
#pragma unroll
      for (int ni = 0; ni < 4; ++ni) {
        int r = wn * 64 + ni * 16 + (lane & 15);
        int sl = ks * 4 + (lane >> 4);
        int p = sl ^ (r & 7);
        bfr[ni] = *(const bf16x8*)&lB[r * 64 + p * 8];
      }
#pragma unroll
      for (int mi = 0; mi < 4; ++mi)
#pragma unroll
        for (int ni = 0; ni < 4; ++ni)
          acc[mi][ni] = __builtin_amdgcn_mfma_f32_16x16x32_bf16(af[mi], bfr[ni], acc[mi][ni], 0, 0, 0);
    }
    __syncthreads();
  }

  if (EPI == 0) {
    __hip_bfloat16* out = projOut + (size_t)z * DIM * DIM;
#pragma unroll
    for (int mi = 0; mi < 4; ++mi) {
      int s0 = bm * 128 + wm * 64 + mi * 16 + ((lane >> 4) << 2);
#pragma unroll
      for (int ni = 0; ni < 4; ++ni) {
        int e = bn * 128 + wn * 64 + ni * 16 + (lane & 15);
#pragma unroll
        for (int j = 0; j < 4; ++j)
          out[(size_t)(s0 + j) * DIM + e] = __float2bfloat16(acc[mi][ni][j]);
      }
    }
  } else {
    int a = z >> 4;
    const float* mk = msk + (size_t)a * DIM * DIM;
    float rmx[4][4], cmx[4];
#pragma unroll
    for (int mi = 0; mi < 4; ++mi)
#pragma unroll
      for (int j = 0; j < 4; ++j) rmx[mi][j] = -INFINITY;
#pragma unroll
    for (int ni = 0; ni < 4; ++ni) cmx[ni] = -INFINITY;
#pragma unroll
    for (int mi = 0; mi < 4; ++mi) {
      int s0 = bm * 128 + wm * 64 + mi * 16 + ((lane >> 4) << 2);
#pragma unroll
      for (int ni = 0; ni < 4; ++ni) {
        int t = bn * 128 + wn * 64 + ni * 16 + (lane & 15);
#pragma unroll
        for (int j = 0; j < 4; ++j) {
          float v = tanhf(acc[mi][ni][j]) + mk[(size_t)(s0 + j) * DIM + t];
          rmx[mi][j] = fmaxf(rmx[mi][j], v);
          cmx[ni] = fmaxf(cmx[ni], v);
        }
      }
    }
    // row-max (over t): reduce across the 16 lanes sharing a row group
#pragma unroll
    for (int mi = 0; mi < 4; ++mi)
#pragma unroll
      for (int j = 0; j < 4; ++j) {
        float r = rmx[mi][j];
        r = fmaxf(r, __shfl_xor(r, 1));
        r = fmaxf(r, __shfl_xor(r, 2));
        r = fmaxf(r, __shfl_xor(r, 4));
        r = fmaxf(r, __shfl_xor(r, 8));
        if ((lane & 15) == 0) {
          int s = bm * 128 + wm * 64 + mi * 16 + ((lane >> 4) << 2) + j;
          atomicMax(&maxS[(size_t)z * DIM + s], fenc(r));
        }
      }
    // col-max (over s): reduce across lane>>4 groups
#pragma unroll
    for (int ni = 0; ni < 4; ++ni) {
      float c = cmx[ni];
      c = fmaxf(c, __shfl_xor(c, 16));
      c = fmaxf(c, __shfl_xor(c, 32));
      if (lane < 16) {
        int t = bn * 128 + wn * 64 + ni * 16 + lane;
        atomicMax(&maxT[(size_t)z * DIM + t], fenc(c));
      }
    }
  }
}

// ---- softmax over the 512 max-logits of each (pair, side) ----
__global__ __launch_bounds__(64) void k_softmax(const unsigned* __restrict__ menc,
                                                float* __restrict__ sc) {
  int pair = blockIdx.x, side = blockIdx.y;
  const unsigned* buf = menc + (size_t)side * 256 * DIM + (size_t)pair * DIM;
  float* out = sc + (size_t)side * 256 * DIM + (size_t)pair * DIM;
  int lane = threadIdx.x;
  float v[8];
  float m = -INFINITY;
#pragma unroll
  for (int k = 0; k < 8; ++k) {
    v[k] = fdec(buf[lane + 64 * k]);
    m = fmaxf(m, v[k]);
  }
#pragma unroll
  for (int off = 1; off < 64; off <<= 1) m = fmaxf(m, __shfl_xor(m, off));
  float s = 0.f;
#pragma unroll
  for (int k = 0; k < 8; ++k) {
    v[k] = expf(v[k] - m);
    s += v[k];
  }
#pragma unroll
  for (int off = 1; off < 64; off <<= 1) s += __shfl_xor(s, off);
  float inv = 1.0f / s;
#pragma unroll
  for (int k = 0; k < 8; ++k) out[lane + 64 * k] = v[k] * inv;
}

// ---- attention-weighted pooling: out[pair][d] = sum_s mat[d][s] * score[pair][s]
// block = (d-chunk of 64, batch y, side); covers all 16 partners of y.
__global__ __launch_bounds__(256) void k_pool(const float* __restrict__ A,
                                              const float* __restrict__ B,
                                              const float* __restrict__ sc,
                                              float* __restrict__ out) {
  __shared__ float ta[128][65];  // [s][d] transposed stage, pad 65 for banks
  __shared__ float ts[16][128];  // scores slice for 16 partners
  int t = threadIdx.x;
  int d0 = blockIdx.x * 64;
  int y = blockIdx.y, side = blockIdx.z;
  const float* mat = (side ? B : A) + (size_t)y * DIM * DIM;
  const float* scb = sc + (size_t)side * 256 * DIM;
  float* ob = out + (size_t)side * 256 * DIM;
  int dl = t & 63, g = t >> 6;
  float acc[4] = {0.f, 0.f, 0.f, 0.f};
  for (int st = 0; st < 4; ++st) {
    __syncthreads();
#pragma unroll
    for (int i = 0; i < 32; ++i) {
      int idx = t + 256 * i;
      int r = idx >> 7, c = idx & 127;
      ta[c][r] = mat[(size_t)(d0 + r) * DIM + st * 128 + c];
    }
#pragma unroll
    for (int i = 0; i < 8; ++i) {
      int idx = t + 256 * i;
      int p = idx >> 7, s = idx & 127;
      int pair = side ? (p * 16 + y) : (y * 16 + p);
      ts[p][s] = scb[(size_t)pair * DIM + st * 128 + s];
    }
    __syncthreads();
    for (int s = 0; s < 128; ++s) {
      float v = ta[s][dl];
#pragma unroll
      for (int i = 0; i < 4; ++i) acc[i] += v * ts[g * 4 + i][s];
    }
  }
#pragma unroll
  for (int i = 0; i < 4; ++i) {
    int p = g * 4 + i;
    int pair = side ? (p * 16 + y) : (y * 16 + p);
    ob[(size_t)pair * DIM + d0 + dl] = acc[i];
  }
}

extern "C" void kernel_launch(void* const* d_in, const int* in_sizes, int n_in,
                              void* d_out, int out_size, void* d_ws, size_t ws_size,
                              hipStream_t stream) {
  (void)in_sizes; (void)n_in; (void)out_size; (void)ws_size;
  const float* A = (const float*)d_in[0];    // (16, 512, 512) d-major
  const float* B = (const float*)d_in[1];    // (16, 512, 512) d-major
  const float* msk = (const float*)d_in[2];  // (16, 512, 512)
  const float* U = (const float*)d_in[3];    // (512, 512)

  char* w = (char*)d_ws;
  __hip_bfloat16* At = (__hip_bfloat16*)(w + 0);         //  8,388,608 B: [a][s][d]
  __hip_bfloat16* Bt = (__hip_bfloat16*)(w + 8388608);   //  8,388,608 B: [b][t][e]
  __hip_bfloat16* Ut = (__hip_bfloat16*)(w + 16777216);  //    524,288 B: [e][d]
  __hip_bfloat16* Pj = (__hip_bfloat16*)(w + 17301504);  //  8,388,608 B: [a][s][e]
  unsigned* menc = (unsigned*)(w + 25690112);            //  1,048,576 B: maxS | maxT
  float* sc = (float*)(w + 26738688);                    //  1,048,576 B: scores
  unsigned* maxS = menc;
  unsigned* maxT = menc + 256 * DIM;

  k_transpose_bf16<<<dim3(16, 16, 16), dim3(32, 8), 0, stream>>>(A, At);
  k_transpose_bf16<<<dim3(16, 16, 16), dim3(32, 8), 0, stream>>>(B, Bt);
  k_transpose_bf16<<<dim3(16, 16, 1), dim3(32, 8), 0, stream>>>(U, Ut);
  k_init_max<<<1024, 256, 0, stream>>>(menc);
  // proj[a] = At[a] @ Ut^T  (16 batched 512^3)
  k_gemm_bt<0><<<dim3(16, 16), 256, 0, stream>>>(At, Ut, nullptr, Pj, nullptr, nullptr);
  // align maxes: 256 pairs of 512^3 + fused tanh/mask/max
  k_gemm_bt<1><<<dim3(16, 256), 256, 0, stream>>>(Pj, Bt, msk, nullptr, maxS, maxT);
  k_softmax<<<dim3(256, 2), 64, 0, stream>>>(menc, sc);
  k_pool<<<dim3(8, 16, 2), 256, 0, stream>>>(A, B, sc, (float*)d_out);
}

// Round 2
// 201.093 us; speedup vs baseline: 1.2097x; 1.2097x over previous
//
#include <hip/hip_runtime.h>
#include <hip/hip_bf16.h>
#include <stdint.h>

#define DIM 512

typedef __bf16 bf16x8 __attribute__((ext_vector_type(8)));
typedef float f32x4 __attribute__((ext_vector_type(4)));

// ---- monotonic float<->uint encoding for atomicMax on signed floats ----
__device__ __forceinline__ unsigned fenc(float f) {
  unsigned u = __float_as_uint(f);
  return (u & 0x80000000u) ? ~u : (u | 0x80000000u);
}
__device__ __forceinline__ float fdec(unsigned e) {
  unsigned u = (e & 0x80000000u) ? (e & 0x7FFFFFFFu) : ~e;
  return __uint_as_float(u);
}

// ---- fast tanh: 1 - 2/(exp(2x)+1). v_exp_f32 + v_rcp_f32, ~5 VALU ops.
// x->+inf: exp->inf, rcp->0, t->1.  x->-inf: exp->0, t->-1.  |err| ~1e-6.
__device__ __forceinline__ float tanh_fast(float x) {
  float e = __expf(2.0f * x);
  return 1.0f - 2.0f * __builtin_amdgcn_rcpf(e + 1.0f);
}

// ---- transpose last-2-dims + f32->bf16 convert: out[z][i][j] = in[z][j][i] ----
__global__ __launch_bounds__(256) void k_transpose_bf16(const float* __restrict__ in,
                                                        __hip_bfloat16* __restrict__ out) {
  __shared__ float tile[32][33];
  int x0 = blockIdx.x * 32, y0 = blockIdx.y * 32, z = blockIdx.z;
  const float* src = in + (size_t)z * DIM * DIM;
  __hip_bfloat16* dst = out + (size_t)z * DIM * DIM;
  int tx = threadIdx.x, ty = threadIdx.y;
#pragma unroll
  for (int k = 0; k < 4; ++k)
    tile[ty + 8 * k][tx] = src[(size_t)(y0 + ty + 8 * k) * DIM + x0 + tx];
  __syncthreads();
#pragma unroll
  for (int k = 0; k < 4; ++k)
    dst[(size_t)(x0 + ty + 8 * k) * DIM + y0 + tx] = __float2bfloat16(tile[tx][ty + 8 * k]);
}

// ---- init max buffers to enc(-inf) ----
__global__ void k_init_max(unsigned* p) { p[blockIdx.x * 256 + threadIdx.x] = 0x007FFFFFu; }

// ---- async global->LDS, 16B per lane ----
__device__ __forceinline__ void gload_lds16(const __hip_bfloat16* g, __hip_bfloat16* l) {
  __builtin_amdgcn_global_load_lds(
      (const __attribute__((address_space(1))) uint32_t*)g,
      (__attribute__((address_space(3))) uint32_t*)l, 16, 0, 0);
}

// ---- MFMA GEMM: C(128x128 tile) = X(M,K=512 row-major) @ Yt(N,K=512 row-major)^T
// EPI=0: store bf16 proj.  EPI=1: tanh + mask + row/col max -> atomicMax.
template <int EPI>
__global__ __launch_bounds__(256, 4) void k_gemm_bt(
    const __hip_bfloat16* __restrict__ Xbase, const __hip_bfloat16* __restrict__ Ytbase,
    const float* __restrict__ msk, __hip_bfloat16* __restrict__ projOut,
    unsigned* __restrict__ maxS, unsigned* __restrict__ maxT) {
  __shared__ __align__(16) __hip_bfloat16 lA[128 * 64];
  __shared__ __align__(16) __hip_bfloat16 lB[128 * 64];
  const int tid = threadIdx.x;
  const int lane = tid & 63;
  const int wid = tid >> 6;
  const int wm = wid >> 1, wn = wid & 1;
  const int tileid = blockIdx.x;
  const int bm = tileid & 3, bn = tileid >> 2;
  const int z = blockIdx.y;

  const __hip_bfloat16* X;
  const __hip_bfloat16* Yt;
  if (EPI == 0) {
    X = Xbase + (size_t)z * DIM * DIM;
    Yt = Ytbase;
  } else {
    int a = z >> 4, b = z & 15;
    X = Xbase + (size_t)a * DIM * DIM;
    Yt = Ytbase + (size_t)b * DIM * DIM;
  }

  // staging: thread t covers 16B slot (i*256+t); LDS dest is linear (HW requirement),
  // global source column is pre-XOR-swizzled so reads can use the same involution.
  int sl16[4], srow[4], scol[4];
#pragma unroll
  for (int i = 0; i < 4; ++i) {
    int d16 = i * 256 + tid;       // 16B-slot index within 128x64 bf16 tile
    int r = d16 >> 3, p = d16 & 7; // row, physical 16B slot in row
    sl16[i] = d16;
    srow[i] = r;
    scol[i] = (p ^ (r & 7)) * 8;   // logical bf16 column
  }

  f32x4 acc[4][4];
#pragma unroll
  for (int mi = 0; mi < 4; ++mi)
#pragma unroll
    for (int ni = 0; ni < 4; ++ni) acc[mi][ni] = (f32x4){0.f, 0.f, 0.f, 0.f};

  const int rowA = bm * 128, rowB = bn * 128;
  for (int k0 = 0; k0 < DIM; k0 += 64) {
#pragma unroll
    for (int i = 0; i < 4; ++i) {
      gload_lds16(X + (size_t)(rowA + srow[i]) * DIM + k0 + scol[i], &lA[sl16[i] * 8]);
      gload_lds16(Yt + (size_t)(rowB + srow[i]) * DIM + k0 + scol[i], &lB[sl16[i] * 8]);
    }
    __syncthreads();
#pragma unroll
    for (int ks = 0; ks < 2; ++ks) {
      bf16x8 af[4], bfr[4];
#pragma unroll
      for (int mi = 0; mi < 4; ++mi) {
        int r = wm * 64 + mi * 16 + (lane & 15);
        int sl = ks * 4 + (lane >> 4);
        int p = sl ^ (r & 7);
        af[mi] = *(const bf16x8*)&lA[r * 64 + p * 8];
      }
#pragma unroll
      for (int ni = 0; ni < 4; ++ni) {
        int r = wn * 64 + ni * 16 + (lane & 15);
        int sl = ks * 4 + (lane >> 4);
        int p = sl ^ (r & 7);
        bfr[ni] = *(const bf16x8*)&lB[r * 64 + p * 8];
      }
#pragma unroll
      for (int mi = 0; mi < 4; ++mi)
#pragma unroll
        for (int ni = 0; ni < 4; ++ni)
          acc[mi][ni] = __builtin_amdgcn_mfma_f32_16x16x32_bf16(af[mi], bfr[ni], acc[mi][ni], 0, 0, 0);
    }
    __syncthreads();
  }

  if (EPI == 0) {
    __hip_bfloat16* out = projOut + (size_t)z * DIM * DIM;
#pragma unroll
    for (int mi = 0; mi < 4; ++mi) {
      int s0 = bm * 128 + wm * 64 + mi * 16 + ((lane >> 4) << 2);
#pragma unroll
      for (int ni = 0; ni < 4; ++ni) {
        int e = bn * 128 + wn * 64 + ni * 16 + (lane & 15);
#pragma unroll
        for (int j = 0; j < 4; ++j)
          out[(size_t)(s0 + j) * DIM + e] = __float2bfloat16(acc[mi][ni][j]);
      }
    }
  } else {
    int a = z >> 4;
    const float* mk = msk + (size_t)a * DIM * DIM;
    float rmx[4][4], cmx[4];
#pragma unroll
    for (int mi = 0; mi < 4; ++mi)
#pragma unroll
      for (int j = 0; j < 4; ++j) rmx[mi][j] = -INFINITY;
#pragma unroll
    for (int ni = 0; ni < 4; ++ni) cmx[ni] = -INFINITY;
#pragma unroll
    for (int mi = 0; mi < 4; ++mi) {
      int s0 = bm * 128 + wm * 64 + mi * 16 + ((lane >> 4) << 2);
#pragma unroll
      for (int ni = 0; ni < 4; ++ni) {
        int t = bn * 128 + wn * 64 + ni * 16 + (lane & 15);
#pragma unroll
        for (int j = 0; j < 4; ++j) {
          float v = tanh_fast(acc[mi][ni][j]) + mk[(size_t)(s0 + j) * DIM + t];
          rmx[mi][j] = fmaxf(rmx[mi][j], v);
          cmx[ni] = fmaxf(cmx[ni], v);
        }
      }
    }
    // row-max (over t): reduce across the 16 lanes sharing a row group
#pragma unroll
    for (int mi = 0; mi < 4; ++mi)
#pragma unroll
      for (int j = 0; j < 4; ++j) {
        float r = rmx[mi][j];
        r = fmaxf(r, __shfl_xor(r, 1));
        r = fmaxf(r, __shfl_xor(r, 2));
        r = fmaxf(r, __shfl_xor(r, 4));
        r = fmaxf(r, __shfl_xor(r, 8));
        if ((lane & 15) == 0) {
          int s = bm * 128 + wm * 64 + mi * 16 + ((lane >> 4) << 2) + j;
          atomicMax(&maxS[(size_t)z * DIM + s], fenc(r));
        }
      }
    // col-max (over s): reduce across lane>>4 groups
#pragma unroll
    for (int ni = 0; ni < 4; ++ni) {
      float c = cmx[ni];
      c = fmaxf(c, __shfl_xor(c, 16));
      c = fmaxf(c, __shfl_xor(c, 32));
      if (lane < 16) {
        int t = bn * 128 + wn * 64 + ni * 16 + lane;
        atomicMax(&maxT[(size_t)z * DIM + t], fenc(c));
      }
    }
  }
}

// ---- softmax over the 512 max-logits of each (pair, side) ----
__global__ __launch_bounds__(64) void k_softmax(const unsigned* __restrict__ menc,
                                                float* __restrict__ sc) {
  int pair = blockIdx.x, side = blockIdx.y;
  const unsigned* buf = menc + (size_t)side * 256 * DIM + (size_t)pair * DIM;
  float* out = sc + (size_t)side * 256 * DIM + (size_t)pair * DIM;
  int lane = threadIdx.x;
  float v[8];
  float m = -INFINITY;
#pragma unroll
  for (int k = 0; k < 8; ++k) {
    v[k] = fdec(buf[lane + 64 * k]);
    m = fmaxf(m, v[k]);
  }
#pragma unroll
  for (int off = 1; off < 64; off <<= 1) m = fmaxf(m, __shfl_xor(m, off));
  float s = 0.f;
#pragma unroll
  for (int k = 0; k < 8; ++k) {
    v[k] = expf(v[k] - m);
    s += v[k];
  }
#pragma unroll
  for (int off = 1; off < 64; off <<= 1) s += __shfl_xor(s, off);
  float inv = 1.0f / s;
#pragma unroll
  for (int k = 0; k < 8; ++k) out[lane + 64 * k] = v[k] * inv;
}

// ---- attention-weighted pooling: out[pair][d] = sum_s mat[d][s] * score[pair][s]
// block = (d-chunk of 64, batch y, side); covers all 16 partners of y.
__global__ __launch_bounds__(256) void k_pool(const float* __restrict__ A,
                                              const float* __restrict__ B,
                                              const float* __restrict__ sc,
                                              float* __restrict__ out) {
  __shared__ float ta[128][65];  // [s][d] transposed stage, pad 65 for banks
  __shared__ float ts[16][128];  // scores slice for 16 partners
  int t = threadIdx.x;
  int d0 = blockIdx.x * 64;
  int y = blockIdx.y, side = blockIdx.z;
  const float* mat = (side ? B : A) + (size_t)y * DIM * DIM;
  const float* scb = sc + (size_t)side * 256 * DIM;
  float* ob = out + (size_t)side * 256 * DIM;
  int dl = t & 63, g = t >> 6;
  float acc[4] = {0.f, 0.f, 0.f, 0.f};
  for (int st = 0; st < 4; ++st) {
    __syncthreads();
#pragma unroll
    for (int i = 0; i < 32; ++i) {
      int idx = t + 256 * i;
      int r = idx >> 7, c = idx & 127;
      ta[c][r] = mat[(size_t)(d0 + r) * DIM + st * 128 + c];
    }
#pragma unroll
    for (int i = 0; i < 8; ++i) {
      int idx = t + 256 * i;
      int p = idx >> 7, s = idx & 127;
      int pair = side ? (p * 16 + y) : (y * 16 + p);
      ts[p][s] = scb[(size_t)pair * DIM + st * 128 + s];
    }
    __syncthreads();
    for (int s = 0; s < 128; ++s) {
      float v = ta[s][dl];
#pragma unroll
      for (int i = 0; i < 4; ++i) acc[i] += v * ts[g * 4 + i][s];
    }
  }
#pragma unroll
  for (int i = 0; i < 4; ++i) {
    int p = g * 4 + i;
    int pair = side ? (p * 16 + y) : (y * 16 + p);
    ob[(size_t)pair * DIM + d0 + dl] = acc[i];
  }
}

extern "C" void kernel_launch(void* const* d_in, const int* in_sizes, int n_in,
                              void* d_out, int out_size, void* d_ws, size_t ws_size,
                              hipStream_t stream) {
  (void)in_sizes; (void)n_in; (void)out_size; (void)ws_size;
  const float* A = (const float*)d_in[0];    // (16, 512, 512) d-major
  const float* B = (const float*)d_in[1];    // (16, 512, 512) d-major
  const float* msk = (const float*)d_in[2];  // (16, 512, 512)
  const float* U = (const float*)d_in[3];    // (512, 512)

  char* w = (char*)d_ws;
  __hip_bfloat16* At = (__hip_bfloat16*)(w + 0);         //  8,388,608 B: [a][s][d]
  __hip_bfloat16* Bt = (__hip_bfloat16*)(w + 8388608);   //  8,388,608 B: [b][t][e]
  __hip_bfloat16* Ut = (__hip_bfloat16*)(w + 16777216);  //    524,288 B: [e][d]
  __hip_bfloat16* Pj = (__hip_bfloat16*)(w + 17301504);  //  8,388,608 B: [a][s][e]
  unsigned* menc = (unsigned*)(w + 25690112);            //  1,048,576 B: maxS | maxT
  float* sc = (float*)(w + 26738688);                    //  1,048,576 B: scores
  unsigned* maxS = menc;
  unsigned* maxT = menc + 256 * DIM;

  k_transpose_bf16<<<dim3(16, 16, 16), dim3(32, 8), 0, stream>>>(A, At);
  k_transpose_bf16<<<dim3(16, 16, 16), dim3(32, 8), 0, stream>>>(B, Bt);
  k_transpose_bf16<<<dim3(16, 16, 1), dim3(32, 8), 0, stream>>>(U, Ut);
  k_init_max<<<1024, 256, 0, stream>>>(menc);
  // proj[a] = At[a] @ Ut^T  (16 batched 512^3)
  k_gemm_bt<0><<<dim3(16, 16), 256, 0, stream>>>(At, Ut, nullptr, Pj, nullptr, nullptr);
  // align maxes: 256 pairs of 512^3 + fused tanh/mask/max
  k_gemm_bt<1><<<dim3(16, 256), 256, 0, stream>>>(Pj, Bt, msk, nullptr, maxS, maxT);
  k_softmax<<<dim3(256, 2), 64, 0, stream>>>(menc, sc);
  k_pool<<<dim3(8, 16, 2), 256, 0, stream>>>(A, B, sc, (float*)d_out);
}

// Round 3
// 172.126 us; speedup vs baseline: 1.4132x; 1.1683x over previous
//
#include <hip/hip_runtime.h>
#include <hip/hip_bf16.h>
#include <stdint.h>

#define DIM 512

typedef __bf16 bf16x8 __attribute__((ext_vector_type(8)));
typedef float f32x4 __attribute__((ext_vector_type(4)));

// ---- monotonic float<->uint encoding for atomicMax on signed floats ----
__device__ __forceinline__ unsigned fenc(float f) {
  unsigned u = __float_as_uint(f);
  return (u & 0x80000000u) ? ~u : (u | 0x80000000u);
}
__device__ __forceinline__ float fdec(unsigned e) {
  unsigned u = (e & 0x80000000u) ? (e & 0x7FFFFFFFu) : ~e;
  return __uint_as_float(u);
}

// ---- fast tanh: 1 - 2/(exp(2x)+1). ~5 VALU ops, exact at saturated tails.
__device__ __forceinline__ float tanh_fast(float x) {
  float e = __expf(2.0f * x);
  return 1.0f - 2.0f * __builtin_amdgcn_rcpf(e + 1.0f);
}

// ---- transpose last-2-dims + f32->bf16 convert: out[z][i][j] = in[z][j][i] ----
__global__ __launch_bounds__(256) void k_transpose_bf16(const float* __restrict__ in,
                                                        __hip_bfloat16* __restrict__ out) {
  __shared__ float tile[32][33];
  int x0 = blockIdx.x * 32, y0 = blockIdx.y * 32, z = blockIdx.z;
  const float* src = in + (size_t)z * DIM * DIM;
  __hip_bfloat16* dst = out + (size_t)z * DIM * DIM;
  int tx = threadIdx.x, ty = threadIdx.y;
#pragma unroll
  for (int k = 0; k < 4; ++k)
    tile[ty + 8 * k][tx] = src[(size_t)(y0 + ty + 8 * k) * DIM + x0 + tx];
  __syncthreads();
#pragma unroll
  for (int k = 0; k < 4; ++k)
    dst[(size_t)(x0 + ty + 8 * k) * DIM + y0 + tx] = __float2bfloat16(tile[tx][ty + 8 * k]);
}

// ---- init max buffers to enc(-inf) ----
__global__ void k_init_max(unsigned* p) { p[blockIdx.x * 256 + threadIdx.x] = 0x007FFFFFu; }

// ---- async global->LDS, 16B per lane ----
__device__ __forceinline__ void gload_lds16(const __hip_bfloat16* g, __hip_bfloat16* l) {
  __builtin_amdgcn_global_load_lds(
      (const __attribute__((address_space(1))) uint32_t*)g,
      (__attribute__((address_space(3))) uint32_t*)l, 16, 0, 0);
}

// ---- proj GEMM, M flattened to 8192: Pj[8192][512] = At[8192][512] @ Ut[512][512]^T
// 64x64 tiles, 1024 blocks for occupancy (the old 128^2 version had only 256 blocks).
__global__ __launch_bounds__(256, 4) void k_proj64(const __hip_bfloat16* __restrict__ At,
                                                   const __hip_bfloat16* __restrict__ Ut,
                                                   __hip_bfloat16* __restrict__ Pj) {
  __shared__ __align__(16) __hip_bfloat16 lA[64 * 64];
  __shared__ __align__(16) __hip_bfloat16 lB[64 * 64];
  const int tid = threadIdx.x, lane = tid & 63, wid = tid >> 6;
  const int wm = wid >> 1, wn = wid & 1;
  const int rowA = blockIdx.x * 64, rowB = blockIdx.y * 64;

  int sl16[2], srow[2], scol[2];
#pragma unroll
  for (int i = 0; i < 2; ++i) {
    int d16 = i * 256 + tid;
    int r = d16 >> 3, p = d16 & 7;
    sl16[i] = d16;
    srow[i] = r;
    scol[i] = (p ^ (r & 7)) * 8;
  }

  f32x4 acc[2][2];
#pragma unroll
  for (int mi = 0; mi < 2; ++mi)
#pragma unroll
    for (int ni = 0; ni < 2; ++ni) acc[mi][ni] = (f32x4){0.f, 0.f, 0.f, 0.f};

  for (int k0 = 0; k0 < DIM; k0 += 64) {
#pragma unroll
    for (int i = 0; i < 2; ++i) {
      gload_lds16(At + (size_t)(rowA + srow[i]) * DIM + k0 + scol[i], &lA[sl16[i] * 8]);
      gload_lds16(Ut + (size_t)(rowB + srow[i]) * DIM + k0 + scol[i], &lB[sl16[i] * 8]);
    }
    __syncthreads();
#pragma unroll
    for (int ks = 0; ks < 2; ++ks) {
      bf16x8 af[2], bfr[2];
#pragma unroll
      for (int mi = 0; mi < 2; ++mi) {
        int r = wm * 32 + mi * 16 + (lane & 15);
        int p = (ks * 4 + (lane >> 4)) ^ (r & 7);
        af[mi] = *(const bf16x8*)&lA[r * 64 + p * 8];
      }
#pragma unroll
      for (int ni = 0; ni < 2; ++ni) {
        int r = wn * 32 + ni * 16 + (lane & 15);
        int p = (ks * 4 + (lane >> 4)) ^ (r & 7);
        bfr[ni] = *(const bf16x8*)&lB[r * 64 + p * 8];
      }
#pragma unroll
      for (int mi = 0; mi < 2; ++mi)
#pragma unroll
        for (int ni = 0; ni < 2; ++ni)
          acc[mi][ni] = __builtin_amdgcn_mfma_f32_16x16x32_bf16(af[mi], bfr[ni], acc[mi][ni], 0, 0, 0);
    }
    __syncthreads();
  }

#pragma unroll
  for (int mi = 0; mi < 2; ++mi) {
    int r0 = rowA + wm * 32 + mi * 16 + ((lane >> 4) << 2);
#pragma unroll
    for (int ni = 0; ni < 2; ++ni) {
      int c = rowB + wn * 32 + ni * 16 + (lane & 15);
#pragma unroll
      for (int j = 0; j < 4; ++j)
        Pj[(size_t)(r0 + j) * DIM + c] = __float2bfloat16(acc[mi][ni][j]);
    }
  }
}

// ---- align GEMM + fused tanh/mask/max epilogue. Each block computes the
// 128x128 tile for TWO b values (shared Pj stage, shared mask loads).
// Grid 2048, decoded so each XCD (bid&7) owns 2 a's -> mask+Pj are L2-resident.
__global__ __launch_bounds__(256, 2) void k_align(const __hip_bfloat16* __restrict__ Pj,
                                                  const __hip_bfloat16* __restrict__ Bt,
                                                  const float* __restrict__ msk,
                                                  unsigned* __restrict__ maxS,
                                                  unsigned* __restrict__ maxT) {
  __shared__ __align__(16) __hip_bfloat16 lA[128 * 64];
  __shared__ __align__(16) __hip_bfloat16 lB0[128 * 64];
  __shared__ __align__(16) __hip_bfloat16 lB1[128 * 64];
  const int tid = threadIdx.x;
  const int lane = tid & 63;
  const int wid = tid >> 6;
  const int wm = wid >> 1, wn = wid & 1;

  // bijective decode: xcd = bid&7 owns a in {xcd, xcd+8}
  const int bid = blockIdx.x;
  const int xcd = bid & 7;
  const int slot = bid >> 3;              // [0,256)
  const int a = xcd + 8 * (slot >> 7);    // 2 a's per xcd
  const int rem = slot & 127;             // [0,128)
  const int bp = rem >> 4;                // [0,8): b-pair
  const int x = rem & 15;
  const int bm = x & 3, bn = x >> 2;
  const int b0 = bp * 2, b1 = b0 + 1;

  const __hip_bfloat16* X = Pj + (size_t)a * DIM * DIM;
  const __hip_bfloat16* Y0 = Bt + (size_t)b0 * DIM * DIM;
  const __hip_bfloat16* Y1 = Bt + (size_t)b1 * DIM * DIM;

  int sl16[4], srow[4], scol[4];
#pragma unroll
  for (int i = 0; i < 4; ++i) {
    int d16 = i * 256 + tid;
    int r = d16 >> 3, p = d16 & 7;
    sl16[i] = d16;
    srow[i] = r;
    scol[i] = (p ^ (r & 7)) * 8;
  }

  f32x4 acc0[4][4], acc1[4][4];
#pragma unroll
  for (int mi = 0; mi < 4; ++mi)
#pragma unroll
    for (int ni = 0; ni < 4; ++ni) {
      acc0[mi][ni] = (f32x4){0.f, 0.f, 0.f, 0.f};
      acc1[mi][ni] = (f32x4){0.f, 0.f, 0.f, 0.f};
    }

  const int rowA = bm * 128, rowB = bn * 128;
  for (int k0 = 0; k0 < DIM; k0 += 64) {
#pragma unroll
    for (int i = 0; i < 4; ++i) {
      gload_lds16(X + (size_t)(rowA + srow[i]) * DIM + k0 + scol[i], &lA[sl16[i] * 8]);
      gload_lds16(Y0 + (size_t)(rowB + srow[i]) * DIM + k0 + scol[i], &lB0[sl16[i] * 8]);
      gload_lds16(Y1 + (size_t)(rowB + srow[i]) * DIM + k0 + scol[i], &lB1[sl16[i] * 8]);
    }
    __syncthreads();
#pragma unroll
    for (int ks = 0; ks < 2; ++ks) {
      bf16x8 af[4], b0f[4], b1f[4];
#pragma unroll
      for (int mi = 0; mi < 4; ++mi) {
        int r = wm * 64 + mi * 16 + (lane & 15);
        int p = (ks * 4 + (lane >> 4)) ^ (r & 7);
        af[mi] = *(const bf16x8*)&lA[r * 64 + p * 8];
      }
#pragma unroll
      for (int ni = 0; ni < 4; ++ni) {
        int r = wn * 64 + ni * 16 + (lane & 15);
        int p = (ks * 4 + (lane >> 4)) ^ (r & 7);
        b0f[ni] = *(const bf16x8*)&lB0[r * 64 + p * 8];
        b1f[ni] = *(const bf16x8*)&lB1[r * 64 + p * 8];
      }
#pragma unroll
      for (int mi = 0; mi < 4; ++mi)
#pragma unroll
        for (int ni = 0; ni < 4; ++ni) {
          acc0[mi][ni] = __builtin_amdgcn_mfma_f32_16x16x32_bf16(af[mi], b0f[ni], acc0[mi][ni], 0, 0, 0);
          acc1[mi][ni] = __builtin_amdgcn_mfma_f32_16x16x32_bf16(af[mi], b1f[ni], acc1[mi][ni], 0, 0, 0);
        }
    }
    __syncthreads();
  }

  // ---- epilogue: tanh + mask (loaded once, reused for both b) + row/col max
  const float* mk = msk + (size_t)a * DIM * DIM;
  float rmx0[4][4], rmx1[4][4], cmx0[4], cmx1[4];
#pragma unroll
  for (int mi = 0; mi < 4; ++mi)
#pragma unroll
    for (int j = 0; j < 4; ++j) { rmx0[mi][j] = -INFINITY; rmx1[mi][j] = -INFINITY; }
#pragma unroll
  for (int ni = 0; ni < 4; ++ni) { cmx0[ni] = -INFINITY; cmx1[ni] = -INFINITY; }

#pragma unroll
  for (int mi = 0; mi < 4; ++mi) {
    int s0 = bm * 128 + wm * 64 + mi * 16 + ((lane >> 4) << 2);
#pragma unroll
    for (int ni = 0; ni < 4; ++ni) {
      int t = bn * 128 + wn * 64 + ni * 16 + (lane & 15);
#pragma unroll
      for (int j = 0; j < 4; ++j) {
        float m = mk[(size_t)(s0 + j) * DIM + t];
        float v0 = tanh_fast(acc0[mi][ni][j]) + m;
        float v1 = tanh_fast(acc1[mi][ni][j]) + m;
        rmx0[mi][j] = fmaxf(rmx0[mi][j], v0);
        rmx1[mi][j] = fmaxf(rmx1[mi][j], v1);
        cmx0[ni] = fmaxf(cmx0[ni], v0);
        cmx1[ni] = fmaxf(cmx1[ni], v1);
      }
    }
  }

  const int z0 = a * 16 + b0, z1 = a * 16 + b1;
  // row-max over t: reduce across the 16 lanes of each row group
#pragma unroll
  for (int mi = 0; mi < 4; ++mi)
#pragma unroll
    for (int j = 0; j < 4; ++j) {
      float r0 = rmx0[mi][j], r1 = rmx1[mi][j];
      r0 = fmaxf(r0, __shfl_xor(r0, 1));
      r0 = fmaxf(r0, __shfl_xor(r0, 2));
      r0 = fmaxf(r0, __shfl_xor(r0, 4));
      r0 = fmaxf(r0, __shfl_xor(r0, 8));
      r1 = fmaxf(r1, __shfl_xor(r1, 1));
      r1 = fmaxf(r1, __shfl_xor(r1, 2));
      r1 = fmaxf(r1, __shfl_xor(r1, 4));
      r1 = fmaxf(r1, __shfl_xor(r1, 8));
      if ((lane & 15) == 0) {
        int s = bm * 128 + wm * 64 + mi * 16 + ((lane >> 4) << 2) + j;
        atomicMax(&maxS[(size_t)z0 * DIM + s], fenc(r0));
        atomicMax(&maxS[(size_t)z1 * DIM + s], fenc(r1));
      }
    }
  // col-max over s: reduce across the 4 row groups
#pragma unroll
  for (int ni = 0; ni < 4; ++ni) {
    float c0 = cmx0[ni], c1 = cmx1[ni];
    c0 = fmaxf(c0, __shfl_xor(c0, 16));
    c0 = fmaxf(c0, __shfl_xor(c0, 32));
    c1 = fmaxf(c1, __shfl_xor(c1, 16));
    c1 = fmaxf(c1, __shfl_xor(c1, 32));
    if (lane < 16) {
      int t = bn * 128 + wn * 64 + ni * 16 + lane;
      atomicMax(&maxT[(size_t)z0 * DIM + t], fenc(c0));
      atomicMax(&maxT[(size_t)z1 * DIM + t], fenc(c1));
    }
  }
}

// ---- softmax over the 512 max-logits of each (pair, side) ----
__global__ __launch_bounds__(64) void k_softmax(const unsigned* __restrict__ menc,
                                                float* __restrict__ sc) {
  int pair = blockIdx.x, side = blockIdx.y;
  const unsigned* buf = menc + (size_t)side * 256 * DIM + (size_t)pair * DIM;
  float* out = sc + (size_t)side * 256 * DIM + (size_t)pair * DIM;
  int lane = threadIdx.x;
  float v[8];
  float m = -INFINITY;
#pragma unroll
  for (int k = 0; k < 8; ++k) {
    v[k] = fdec(buf[lane + 64 * k]);
    m = fmaxf(m, v[k]);
  }
#pragma unroll
  for (int off = 1; off < 64; off <<= 1) m = fmaxf(m, __shfl_xor(m, off));
  float s = 0.f;
#pragma unroll
  for (int k = 0; k < 8; ++k) {
    v[k] = expf(v[k] - m);
    s += v[k];
  }
#pragma unroll
  for (int off = 1; off < 64; off <<= 1) s += __shfl_xor(s, off);
  float inv = 1.0f / s;
#pragma unroll
  for (int k = 0; k < 8; ++k) out[lane + 64 * k] = v[k] * inv;
}

// ---- attention-weighted pooling: out[pair][d] = sum_s mat[d][s] * score[pair][s]
__global__ __launch_bounds__(256) void k_pool(const float* __restrict__ A,
                                              const float* __restrict__ B,
                                              const float* __restrict__ sc,
                                              float* __restrict__ out) {
  __shared__ float ta[128][65];
  __shared__ float ts[16][128];
  int t = threadIdx.x;
  int d0 = blockIdx.x * 64;
  int y = blockIdx.y, side = blockIdx.z;
  const float* mat = (side ? B : A) + (size_t)y * DIM * DIM;
  const float* scb = sc + (size_t)side * 256 * DIM;
  float* ob = out + (size_t)side * 256 * DIM;
  int dl = t & 63, g = t >> 6;
  float acc[4] = {0.f, 0.f, 0.f, 0.f};
  for (int st = 0; st < 4; ++st) {
    __syncthreads();
#pragma unroll
    for (int i = 0; i < 32; ++i) {
      int idx = t + 256 * i;
      int r = idx >> 7, c = idx & 127;
      ta[c][r] = mat[(size_t)(d0 + r) * DIM + st * 128 + c];
    }
#pragma unroll
    for (int i = 0; i < 8; ++i) {
      int idx = t + 256 * i;
      int p = idx >> 7, s = idx & 127;
      int pair = side ? (p * 16 + y) : (y * 16 + p);
      ts[p][s] = scb[(size_t)pair * DIM + st * 128 + s];
    }
    __syncthreads();
    for (int s = 0; s < 128; ++s) {
      float v = ta[s][dl];
#pragma unroll
      for (int i = 0; i < 4; ++i) acc[i] += v * ts[g * 4 + i][s];
    }
  }
#pragma unroll
  for (int i = 0; i < 4; ++i) {
    int p = g * 4 + i;
    int pair = side ? (p * 16 + y) : (y * 16 + p);
    ob[(size_t)pair * DIM + d0 + dl] = acc[i];
  }
}

extern "C" void kernel_launch(void* const* d_in, const int* in_sizes, int n_in,
                              void* d_out, int out_size, void* d_ws, size_t ws_size,
                              hipStream_t stream) {
  (void)in_sizes; (void)n_in; (void)out_size; (void)ws_size;
  const float* A = (const float*)d_in[0];    // (16, 512, 512) d-major
  const float* B = (const float*)d_in[1];    // (16, 512, 512) d-major
  const float* msk = (const float*)d_in[2];  // (16, 512, 512)
  const float* U = (const float*)d_in[3];    // (512, 512)

  char* w = (char*)d_ws;
  __hip_bfloat16* At = (__hip_bfloat16*)(w + 0);         //  8 MB: [a][s][d] == [8192][512]
  __hip_bfloat16* Bt = (__hip_bfloat16*)(w + 8388608);   //  8 MB: [b][t][e]
  __hip_bfloat16* Ut = (__hip_bfloat16*)(w + 16777216);  //  512 KB: [e][d]
  __hip_bfloat16* Pj = (__hip_bfloat16*)(w + 17301504);  //  8 MB: [a][s][e] == [8192][512]
  unsigned* menc = (unsigned*)(w + 25690112);            //  1 MB: maxS | maxT
  float* sc = (float*)(w + 26738688);                    //  1 MB: scores
  unsigned* maxS = menc;
  unsigned* maxT = menc + 256 * DIM;

  k_transpose_bf16<<<dim3(16, 16, 16), dim3(32, 8), 0, stream>>>(A, At);
  k_transpose_bf16<<<dim3(16, 16, 16), dim3(32, 8), 0, stream>>>(B, Bt);
  k_transpose_bf16<<<dim3(16, 16, 1), dim3(32, 8), 0, stream>>>(U, Ut);
  k_init_max<<<1024, 256, 0, stream>>>(menc);
  k_proj64<<<dim3(128, 8), 256, 0, stream>>>(At, Ut, Pj);
  k_align<<<2048, 256, 0, stream>>>(Pj, Bt, msk, maxS, maxT);
  k_softmax<<<dim3(256, 2), 64, 0, stream>>>(menc, sc);
  k_pool<<<dim3(8, 16, 2), 256, 0, stream>>>(A, B, sc, (float*)d_out);
}